// Round 4
// baseline (694.086 us; speedup 1.0000x reference)
//
#include <hip/hip_runtime.h>

// ---------- bf16 helpers (raw ushort representation) ----------
__device__ __forceinline__ float bf2f(unsigned short u) {
    union { unsigned int i; float f; } v;
    v.i = ((unsigned int)u) << 16;
    return v.f;
}
__device__ __forceinline__ unsigned short f2bf(float f) {
    union { float f; unsigned int i; } v;
    v.f = f;
    unsigned int r = (v.i + 0x7fffu + ((v.i >> 16) & 1u)) >> 16;
    return (unsigned short)r;
}

typedef __attribute__((ext_vector_type(8))) short short8;
typedef __attribute__((ext_vector_type(4))) float floatx4;

#define GLOBAL_AS __attribute__((address_space(1)))
#define LDS_AS __attribute__((address_space(3)))

static constexpr int Bdim = 8;
static constexpr int Tdim = 2048;
static constexpr int Cdim = 1024;
static constexpr int Edim = 4096;
static constexpr int Mdim = Bdim * Tdim;  // 16384

// ---------- weight transpose + cast: src fp32 (K x N) -> dst bf16 (N x K) ----------
__global__ __launch_bounds__(256) void transpose_f2b(
    const float* __restrict__ src, unsigned short* __restrict__ dst, int K, int N) {
    __shared__ float tile[32][33];
    int n0 = blockIdx.x * 32;
    int k0 = blockIdx.y * 32;
    int tx = threadIdx.x & 31;
    int ty = threadIdx.x >> 5;  // 0..7
#pragma unroll
    for (int i = 0; i < 32; i += 8)
        tile[ty + i][tx] = src[(size_t)(k0 + ty + i) * N + n0 + tx];
    __syncthreads();
#pragma unroll
    for (int i = 0; i < 32; i += 8)
        dst[(size_t)(n0 + ty + i) * K + k0 + tx] = f2bf(tile[tx][ty + i]);
}

// ---------- rmsnorm1 inverse-RMS only: rinv[row] = rsqrt(mean(x^2)+eps) ----------
__global__ __launch_bounds__(256) void rms_inv_kernel(
    const float* __restrict__ x, float* __restrict__ rinv) {
    int row = blockIdx.x;
    int tid = threadIdx.x;
    float4 v = ((const float4*)(x + (size_t)row * Cdim))[tid];
    float s = v.x * v.x + v.y * v.y + v.z * v.z + v.w * v.w;
#pragma unroll
    for (int o = 32; o > 0; o >>= 1) s += __shfl_down(s, o, 64);
    __shared__ float ps[4];
    if ((tid & 63) == 0) ps[tid >> 6] = s;
    __syncthreads();
    if (tid == 0) {
        float tot = ps[0] + ps[1] + ps[2] + ps[3];
        rinv[row] = rsqrtf(tot * (1.0f / (float)Cdim) + 1e-6f);
    }
}

// ---------- cumsum phase A: per-chunk sums of y = x*rinv*w. 1024 blocks ----------
__global__ __launch_bounds__(256) void chunk_sums(
    const float* __restrict__ x, const float* __restrict__ rinv,
    const float* __restrict__ w, float* __restrict__ P) {
    int idx = blockIdx.x;
    int cb = idx & 3;
    int k = (idx >> 2) & 31;
    int b = idx >> 7;
    int c = cb * 256 + threadIdx.x;
    float wc = w[c];
    const float* base = x + ((size_t)b * Tdim + k * 64) * Cdim + c;
    const float* rbase = rinv + (size_t)b * Tdim + k * 64;
    float s = 0.f;
#pragma unroll 8
    for (int t = 0; t < 64; t++) s += base[(size_t)t * Cdim] * rbase[t];
    P[((size_t)b * 32 + k) * Cdim + c] = s * wc;
}

// ---------- cumsum phase B: exclusive scan of 32 chunk sums per (b,c) chain ----------
__global__ __launch_bounds__(256) void chunk_scan(float* __restrict__ P) {
    int g = blockIdx.x * 256 + threadIdx.x;  // 0..8191
    int b = g >> 10;
    int c = g & 1023;
    float* p = P + (size_t)b * 32 * Cdim + c;
    float run = 0.f;
#pragma unroll
    for (int k = 0; k < 32; k++) {
        float v = p[(size_t)k * Cdim];
        p[(size_t)k * Cdim] = run;
        run += v;
    }
}

// ---------- cumsum phase C: rescan, divide by triangular scaler, emit bf16 state ----------
__global__ __launch_bounds__(256) void cumsum_state(
    const float* __restrict__ x, const float* __restrict__ rinv,
    const float* __restrict__ w, const float* __restrict__ P,
    unsigned short* __restrict__ state) {
    int idx = blockIdx.x;
    int cb = idx & 3;
    int k = (idx >> 2) & 31;
    int b = idx >> 7;
    int c = cb * 256 + threadIdx.x;
    float wc = w[c];
    float acc = P[((size_t)b * 32 + k) * Cdim + c];
    const float* base = x + ((size_t)b * Tdim + k * 64) * Cdim + c;
    const float* rbase = rinv + (size_t)b * Tdim + k * 64;
    unsigned short* sbase = state + ((size_t)b * Tdim + k * 64) * Cdim + c;
#pragma unroll 4
    for (int t = 0; t < 64; t++) {
        acc += base[(size_t)t * Cdim] * rbase[t] * wc;
        int tt = k * 64 + t;
        float inv = 2.0f / ((float)(tt + 1) * (float)(tt + 2));
        sbase[(size_t)t * Cdim] = f2bf(acc * inv);
    }
}

// ---------- rmsnorm2: fp32 in -> bf16 out (GEMM A operand) ----------
__global__ __launch_bounds__(256) void rmsnorm_f2b(
    const float* __restrict__ x, const float* __restrict__ w,
    unsigned short* __restrict__ y) {
    int row = blockIdx.x;
    int tid = threadIdx.x;
    float4 v = ((const float4*)(x + (size_t)row * Cdim))[tid];
    float s = v.x * v.x + v.y * v.y + v.z * v.z + v.w * v.w;
#pragma unroll
    for (int o = 32; o > 0; o >>= 1) s += __shfl_down(s, o, 64);
    __shared__ float ps[4];
    if ((tid & 63) == 0) ps[tid >> 6] = s;
    __syncthreads();
    float tot = ps[0] + ps[1] + ps[2] + ps[3];
    float r = rsqrtf(tot * (1.0f / (float)Cdim) + 1e-6f);
    float4 w4 = ((const float4*)w)[tid];
    ushort4 o;
    o.x = f2bf(v.x * r * w4.x);
    o.y = f2bf(v.y * r * w4.y);
    o.z = f2bf(v.z * r * w4.z);
    o.w = f2bf(v.w * r * w4.w);
    ((ushort4*)(y + (size_t)row * Cdim))[tid] = o;
}

// ---------- bf16 MFMA GEMM (m97 structure): C(MxN) = A(MxK) @ BT^T, bf16 inputs ----------
// 128x128 tile, BK=32, 256 threads (4 waves, 2x2 of 64x64), 16x16x32 MFMA,
// global->LDS staging via global_load_lds width=16 (m93->m97: 517->874 TF).
// EPI 0: Cout(f32) = sigmoid(acc+bias) * extra      (gate*x)
// EPI 1: Cout(bf16) = relu(acc+bias)                (h)
// EPI 2: Cout(f32) = acc + bias + extra             (residual; extra may alias Cout)
template <int EPI>
__global__ __launch_bounds__(256) void gemm_bt(
    const unsigned short* __restrict__ A, const unsigned short* __restrict__ BT,
    const float* __restrict__ bias, const float* __restrict__ extra,
    void* __restrict__ Coutv, int M, int N, int K) {
    __shared__ __attribute__((aligned(16))) unsigned short As[128 * 32];
    __shared__ __attribute__((aligned(16))) unsigned short Bs[128 * 32];

    int tid = threadIdx.x;
    int bn = blockIdx.x, bm = blockIdx.y;
    int wave = tid >> 6, lane = tid & 63;
    int wm = (wave & 1) * 64, wn = (wave >> 1) * 64;
    int lrow = lane & 15;
    int lk = (lane >> 4) << 3;

    const unsigned short* Abase = A + (size_t)bm * 128 * K;
    const unsigned short* Bbase = BT + (size_t)bn * 128 * K;

    floatx4 acc[4][4] = {};

    // staging chunk q in [0,512): row = q>>2, col = (q&3)*8; thread tid does q=tid, q=tid+256.
    // LDS dst = base + q*16B = wave-uniform base + lane*16 (q = wave_base + lane) — HW-legal.
    int qrow = tid >> 2;
    int qcol = (tid & 3) << 3;
    const unsigned short* ArowLo = Abase + (size_t)qrow * K + qcol;
    const unsigned short* ArowHi = Abase + (size_t)(qrow + 64) * K + qcol;
    const unsigned short* BrowLo = Bbase + (size_t)qrow * K + qcol;
    const unsigned short* BrowHi = Bbase + (size_t)(qrow + 64) * K + qcol;

    for (int k0 = 0; k0 < K; k0 += 32) {
        __builtin_amdgcn_global_load_lds((const GLOBAL_AS void*)(ArowLo + k0),
                                         (LDS_AS void*)(As + (size_t)tid * 8), 16, 0, 0);
        __builtin_amdgcn_global_load_lds((const GLOBAL_AS void*)(ArowHi + k0),
                                         (LDS_AS void*)(As + (size_t)(tid + 256) * 8), 16, 0, 0);
        __builtin_amdgcn_global_load_lds((const GLOBAL_AS void*)(BrowLo + k0),
                                         (LDS_AS void*)(Bs + (size_t)tid * 8), 16, 0, 0);
        __builtin_amdgcn_global_load_lds((const GLOBAL_AS void*)(BrowHi + k0),
                                         (LDS_AS void*)(Bs + (size_t)(tid + 256) * 8), 16, 0, 0);
        __syncthreads();  // drains vmcnt (DMA landed) + joins waves

        short8 af[4], bfr[4];
#pragma unroll
        for (int i = 0; i < 4; i++)
            af[i] = *(const short8*)(As + (wm + i * 16 + lrow) * 32 + lk);
#pragma unroll
        for (int j = 0; j < 4; j++)
            bfr[j] = *(const short8*)(Bs + (wn + j * 16 + lrow) * 32 + lk);
#pragma unroll
        for (int i = 0; i < 4; i++)
#pragma unroll
            for (int j = 0; j < 4; j++)
                acc[i][j] = __builtin_amdgcn_mfma_f32_16x16x32_bf16(af[i], bfr[j], acc[i][j], 0, 0, 0);
        __syncthreads();  // all ds_reads done before next iter's DMA overwrites
    }

    // epilogue: C/D layout col=lane&15, row=(lane>>4)*4+reg
    int crow = (lane >> 4) * 4;
    int ccol = lane & 15;
#pragma unroll
    for (int i = 0; i < 4; i++) {
#pragma unroll
        for (int j = 0; j < 4; j++) {
            size_t gm = (size_t)bm * 128 + wm + i * 16 + crow;
            size_t gn = (size_t)bn * 128 + wn + j * 16 + ccol;
            float bsv = bias[gn];
#pragma unroll
            for (int r = 0; r < 4; r++) {
                float v = acc[i][j][r] + bsv;
                size_t off = (gm + r) * (size_t)N + gn;
                if (EPI == 0) {
                    float g = 1.f / (1.f + __expf(-v));
                    ((float*)Coutv)[off] = g * extra[off];
                } else if (EPI == 1) {
                    ((unsigned short*)Coutv)[off] = f2bf(v > 0.f ? v : 0.f);
                } else {
                    ((float*)Coutv)[off] = v + extra[off];
                }
            }
        }
    }
}

// ---------- launch ----------
extern "C" void kernel_launch(void* const* d_in, const int* in_sizes, int n_in,
                              void* d_out, int out_size, void* d_ws, size_t ws_size,
                              hipStream_t stream) {
    const float* x   = (const float*)d_in[0];  // (B,T,C) fp32
    const float* n1w = (const float*)d_in[1];  // (C)
    const float* w1  = (const float*)d_in[2];  // (C,C)
    const float* b1  = (const float*)d_in[3];  // (C)
    const float* n2w = (const float*)d_in[4];  // (C)
    const float* w21 = (const float*)d_in[5];  // (C,E)
    const float* b21 = (const float*)d_in[6];  // (E)
    const float* w22 = (const float*)d_in[7];  // (E,C)
    const float* b22 = (const float*)d_in[8];  // (C)
    float* out = (float*)d_out;                // (B,T,C) fp32

    char* ws = (char*)d_ws;
    const size_t MB = 1024ull * 1024ull;
    unsigned short* state = (unsigned short*)(ws);            // 32MB bf16; reused as hnorm
    unsigned short* w1T   = (unsigned short*)(ws + 32 * MB);  // 2MB  (C x C) bf16
    unsigned short* w21T  = (unsigned short*)(ws + 34 * MB);  // 8MB  (E x C) bf16
    unsigned short* w22T  = (unsigned short*)(ws + 42 * MB);  // 8MB  (C x E) bf16
    float* P              = (float*)(ws + 50 * MB);           // 1MB
    float* rinv           = (float*)(ws + 51 * MB);           // 64KB
    unsigned short* h     = (unsigned short*)(ws + 52 * MB);  // up to 128MB bf16 (sliced)
    float* out1 = out;  // gate*x lives in d_out (fp32); G3 reads then overwrites per-element

    // pick M-slice size for the h buffer based on available workspace
    int slice_rows = Mdim;  // 16384 -> h=128MB (total 180MB); halve until it fits
    while (52 * MB + (size_t)slice_rows * Edim * 2 > ws_size && slice_rows > 1024)
        slice_rows >>= 1;

    // weights -> bf16 (N x K)
    transpose_f2b<<<dim3(Cdim / 32, Cdim / 32), 256, 0, stream>>>(w1, w1T, Cdim, Cdim);
    transpose_f2b<<<dim3(Edim / 32, Cdim / 32), 256, 0, stream>>>(w21, w21T, Cdim, Edim);
    transpose_f2b<<<dim3(Cdim / 32, Edim / 32), 256, 0, stream>>>(w22, w22T, Edim, Cdim);

    // rmsnorm1 scale factors
    rms_inv_kernel<<<Mdim, 256, 0, stream>>>(x, rinv);

    // chunked cumsum of x*rinv*n1w over T, with triangular scaler -> bf16 state
    chunk_sums<<<1024, 256, 0, stream>>>(x, rinv, n1w, P);
    chunk_scan<<<32, 256, 0, stream>>>(P);
    cumsum_state<<<1024, 256, 0, stream>>>(x, rinv, n1w, P, state);

    // G1: out1 = sigmoid(state @ w1 + b1) * x   (fp32 out into d_out)
    gemm_bt<0><<<dim3(Cdim / 128, Mdim / 128), 256, 0, stream>>>(
        state, w1T, b1, x, out1, Mdim, Cdim, Cdim);

    // rmsnorm2(out1) -> bf16 hnorm (reuse state buffer)
    rmsnorm_f2b<<<Mdim, 256, 0, stream>>>(out1, n2w, state);

    // G2/G3 sliced over M to bound the h buffer
    for (int m0 = 0; m0 < Mdim; m0 += slice_rows) {
        gemm_bt<1><<<dim3(Edim / 128, slice_rows / 128), 256, 0, stream>>>(
            state + (size_t)m0 * Cdim, w21T, b21, nullptr, h, slice_rows, Edim, Cdim);
        gemm_bt<2><<<dim3(Cdim / 128, slice_rows / 128), 256, 0, stream>>>(
            h, w22T, b22, out1 + (size_t)m0 * Cdim, out + (size_t)m0 * Cdim,
            slice_rows, Cdim, Edim);
    }
}

// Round 5
// 646.054 us; speedup vs baseline: 1.0743x; 1.0743x over previous
//
#include <hip/hip_runtime.h>

// ---------- bf16 helpers (raw ushort representation) ----------
__device__ __forceinline__ float bf2f(unsigned short u) {
    union { unsigned int i; float f; } v;
    v.i = ((unsigned int)u) << 16;
    return v.f;
}
__device__ __forceinline__ unsigned short f2bf(float f) {
    union { float f; unsigned int i; } v;
    v.f = f;
    unsigned int r = (v.i + 0x7fffu + ((v.i >> 16) & 1u)) >> 16;
    return (unsigned short)r;
}

typedef __attribute__((ext_vector_type(8))) short short8;
typedef __attribute__((ext_vector_type(4))) float floatx4;

#define GLOBAL_AS __attribute__((address_space(1)))
#define LDS_AS __attribute__((address_space(3)))

static constexpr int Bdim = 8;
static constexpr int Tdim = 2048;
static constexpr int Cdim = 1024;
static constexpr int Edim = 4096;
static constexpr int Mdim = Bdim * Tdim;  // 16384

// ---------- weight transpose + cast: src fp32 (K x N) -> dst bf16 (N x K) ----------
__global__ __launch_bounds__(256) void transpose_f2b(
    const float* __restrict__ src, unsigned short* __restrict__ dst, int K, int N) {
    __shared__ float tile[32][33];
    int n0 = blockIdx.x * 32;
    int k0 = blockIdx.y * 32;
    int tx = threadIdx.x & 31;
    int ty = threadIdx.x >> 5;  // 0..7
#pragma unroll
    for (int i = 0; i < 32; i += 8)
        tile[ty + i][tx] = src[(size_t)(k0 + ty + i) * N + n0 + tx];
    __syncthreads();
#pragma unroll
    for (int i = 0; i < 32; i += 8)
        dst[(size_t)(n0 + ty + i) * K + k0 + tx] = f2bf(tile[tx][ty + i]);
}

// ---------- rmsnorm1 inverse-RMS only: rinv[row] = rsqrt(mean(x^2)+eps) ----------
__global__ __launch_bounds__(256) void rms_inv_kernel(
    const float* __restrict__ x, float* __restrict__ rinv) {
    int row = blockIdx.x;
    int tid = threadIdx.x;
    float4 v = ((const float4*)(x + (size_t)row * Cdim))[tid];
    float s = v.x * v.x + v.y * v.y + v.z * v.z + v.w * v.w;
#pragma unroll
    for (int o = 32; o > 0; o >>= 1) s += __shfl_down(s, o, 64);
    __shared__ float ps[4];
    if ((tid & 63) == 0) ps[tid >> 6] = s;
    __syncthreads();
    if (tid == 0) {
        float tot = ps[0] + ps[1] + ps[2] + ps[3];
        rinv[row] = rsqrtf(tot * (1.0f / (float)Cdim) + 1e-6f);
    }
}

// ---------- cumsum phase A: per-chunk sums of y = x*rinv*w. 1024 blocks ----------
__global__ __launch_bounds__(256) void chunk_sums(
    const float* __restrict__ x, const float* __restrict__ rinv,
    const float* __restrict__ w, float* __restrict__ P) {
    int idx = blockIdx.x;
    int cb = idx & 3;
    int k = (idx >> 2) & 31;
    int b = idx >> 7;
    int c = cb * 256 + threadIdx.x;
    float wc = w[c];
    const float* base = x + ((size_t)b * Tdim + k * 64) * Cdim + c;
    const float* rbase = rinv + (size_t)b * Tdim + k * 64;
    float s = 0.f;
#pragma unroll 8
    for (int t = 0; t < 64; t++) s += base[(size_t)t * Cdim] * rbase[t];
    P[((size_t)b * 32 + k) * Cdim + c] = s * wc;
}

// ---------- cumsum phase B: exclusive scan of 32 chunk sums per (b,c) chain ----------
__global__ __launch_bounds__(256) void chunk_scan(float* __restrict__ P) {
    int g = blockIdx.x * 256 + threadIdx.x;  // 0..8191
    int b = g >> 10;
    int c = g & 1023;
    float* p = P + (size_t)b * 32 * Cdim + c;
    float run = 0.f;
#pragma unroll
    for (int k = 0; k < 32; k++) {
        float v = p[(size_t)k * Cdim];
        p[(size_t)k * Cdim] = run;
        run += v;
    }
}

// ---------- cumsum phase C: rescan, divide by triangular scaler, emit bf16 state ----------
__global__ __launch_bounds__(256) void cumsum_state(
    const float* __restrict__ x, const float* __restrict__ rinv,
    const float* __restrict__ w, const float* __restrict__ P,
    unsigned short* __restrict__ state) {
    int idx = blockIdx.x;
    int cb = idx & 3;
    int k = (idx >> 2) & 31;
    int b = idx >> 7;
    int c = cb * 256 + threadIdx.x;
    float wc = w[c];
    float acc = P[((size_t)b * 32 + k) * Cdim + c];
    const float* base = x + ((size_t)b * Tdim + k * 64) * Cdim + c;
    const float* rbase = rinv + (size_t)b * Tdim + k * 64;
    unsigned short* sbase = state + ((size_t)b * Tdim + k * 64) * Cdim + c;
#pragma unroll 4
    for (int t = 0; t < 64; t++) {
        acc += base[(size_t)t * Cdim] * rbase[t] * wc;
        int tt = k * 64 + t;
        float inv = 2.0f / ((float)(tt + 1) * (float)(tt + 2));
        sbase[(size_t)t * Cdim] = f2bf(acc * inv);
    }
}

// ---------- rmsnorm2: fp32 in -> bf16 out (GEMM A operand) ----------
__global__ __launch_bounds__(256) void rmsnorm_f2b(
    const float* __restrict__ x, const float* __restrict__ w,
    unsigned short* __restrict__ y) {
    int row = blockIdx.x;
    int tid = threadIdx.x;
    float4 v = ((const float4*)(x + (size_t)row * Cdim))[tid];
    float s = v.x * v.x + v.y * v.y + v.z * v.z + v.w * v.w;
#pragma unroll
    for (int o = 32; o > 0; o >>= 1) s += __shfl_down(s, o, 64);
    __shared__ float ps[4];
    if ((tid & 63) == 0) ps[tid >> 6] = s;
    __syncthreads();
    float tot = ps[0] + ps[1] + ps[2] + ps[3];
    float r = rsqrtf(tot * (1.0f / (float)Cdim) + 1e-6f);
    float4 w4 = ((const float4*)w)[tid];
    ushort4 o;
    o.x = f2bf(v.x * r * w4.x);
    o.y = f2bf(v.y * r * w4.y);
    o.z = f2bf(v.z * r * w4.z);
    o.w = f2bf(v.w * r * w4.w);
    ((ushort4*)(y + (size_t)row * Cdim))[tid] = o;
}

// ---------- bf16 MFMA GEMM, double-buffered LDS with post-barrier DMA prefetch ----------
// C(MxN) = A(MxK) @ BT^T. 128x128 tile, BK=32, 256 threads (2x2 waves of 64x64),
// 16x16x32 MFMA. One barrier per K-iter; global_load_lds prefetch for iter k+1 is
// issued AFTER the barrier so it stays in flight during iter k's ds_read+MFMA phase
// (the compiler's pre-barrier s_waitcnt vmcnt(0) otherwise kills all overlap).
// EPI 0: Cout(f32) = sigmoid(acc+bias) * extra      (gate*x)
// EPI 1: Cout(bf16) = relu(acc+bias)                (h)
// EPI 2: Cout(f32) = acc + bias + extra             (residual; extra may alias Cout)
template <int EPI>
__global__ __launch_bounds__(256) void gemm_bt(
    const unsigned short* __restrict__ A, const unsigned short* __restrict__ BT,
    const float* __restrict__ bias, const float* __restrict__ extra,
    void* __restrict__ Coutv, int M, int N, int K) {
    __shared__ __attribute__((aligned(16))) unsigned short As[2][128 * 32];
    __shared__ __attribute__((aligned(16))) unsigned short Bs[2][128 * 32];

    int tid = threadIdx.x;
    int bn = blockIdx.x, bm = blockIdx.y;
    int wave = tid >> 6, lane = tid & 63;
    int wm = (wave & 1) * 64, wn = (wave >> 1) * 64;
    int lrow = lane & 15;
    int lk = (lane >> 4) << 3;

    const unsigned short* Abase = A + (size_t)bm * 128 * K;
    const unsigned short* Bbase = BT + (size_t)bn * 128 * K;

    floatx4 acc[4][4] = {};

    // staging chunk q in [0,512): row = q>>2, col = (q&3)*8; thread does q=tid, q=tid+256.
    int qrow = tid >> 2;
    int qcol = (tid & 3) << 3;
    const unsigned short* ArowLo = Abase + (size_t)qrow * K + qcol;
    const unsigned short* ArowHi = Abase + (size_t)(qrow + 64) * K + qcol;
    const unsigned short* BrowLo = Bbase + (size_t)qrow * K + qcol;
    const unsigned short* BrowHi = Bbase + (size_t)(qrow + 64) * K + qcol;

#define STAGE(buf, koff)                                                                   \
    do {                                                                                   \
        __builtin_amdgcn_global_load_lds((const GLOBAL_AS void*)(ArowLo + (koff)),         \
                                         (LDS_AS void*)(As[buf] + (size_t)tid * 8), 16, 0, 0); \
        __builtin_amdgcn_global_load_lds((const GLOBAL_AS void*)(ArowHi + (koff)),         \
                                         (LDS_AS void*)(As[buf] + (size_t)(tid + 256) * 8), 16, 0, 0); \
        __builtin_amdgcn_global_load_lds((const GLOBAL_AS void*)(BrowLo + (koff)),         \
                                         (LDS_AS void*)(Bs[buf] + (size_t)tid * 8), 16, 0, 0); \
        __builtin_amdgcn_global_load_lds((const GLOBAL_AS void*)(BrowHi + (koff)),         \
                                         (LDS_AS void*)(Bs[buf] + (size_t)(tid + 256) * 8), 16, 0, 0); \
    } while (0)

    int iters = K >> 5;
    STAGE(0, 0);  // prologue prefetch into buf 0
    for (int k = 0; k < iters; k++) {
        int cur = k & 1;
        // Drains this wave's outstanding DMA (buf[cur] now valid) and joins waves
        // (prev iter's reads of buf[cur^1] complete -> safe to overwrite below).
        __syncthreads();
        if (k + 1 < iters) STAGE(cur ^ 1, (k + 1) << 5);  // in flight during compute

        short8 af[4], bfr[4];
#pragma unroll
        for (int i = 0; i < 4; i++)
            af[i] = *(const short8*)(As[cur] + (wm + i * 16 + lrow) * 32 + lk);
#pragma unroll
        for (int j = 0; j < 4; j++)
            bfr[j] = *(const short8*)(Bs[cur] + (wn + j * 16 + lrow) * 32 + lk);
#pragma unroll
        for (int i = 0; i < 4; i++)
#pragma unroll
            for (int j = 0; j < 4; j++)
                acc[i][j] = __builtin_amdgcn_mfma_f32_16x16x32_bf16(af[i], bfr[j], acc[i][j], 0, 0, 0);
    }
#undef STAGE

    // epilogue: C/D layout col=lane&15, row=(lane>>4)*4+reg
    int crow = (lane >> 4) * 4;
    int ccol = lane & 15;
#pragma unroll
    for (int i = 0; i < 4; i++) {
#pragma unroll
        for (int j = 0; j < 4; j++) {
            size_t gm = (size_t)bm * 128 + wm + i * 16 + crow;
            size_t gn = (size_t)bn * 128 + wn + j * 16 + ccol;
            float bsv = bias[gn];
#pragma unroll
            for (int r = 0; r < 4; r++) {
                float v = acc[i][j][r] + bsv;
                size_t off = (gm + r) * (size_t)N + gn;
                if (EPI == 0) {
                    float g = 1.f / (1.f + __expf(-v));
                    ((float*)Coutv)[off] = g * extra[off];
                } else if (EPI == 1) {
                    ((unsigned short*)Coutv)[off] = f2bf(v > 0.f ? v : 0.f);
                } else {
                    ((float*)Coutv)[off] = v + extra[off];
                }
            }
        }
    }
}

// ---------- launch ----------
extern "C" void kernel_launch(void* const* d_in, const int* in_sizes, int n_in,
                              void* d_out, int out_size, void* d_ws, size_t ws_size,
                              hipStream_t stream) {
    const float* x   = (const float*)d_in[0];  // (B,T,C) fp32
    const float* n1w = (const float*)d_in[1];  // (C)
    const float* w1  = (const float*)d_in[2];  // (C,C)
    const float* b1  = (const float*)d_in[3];  // (C)
    const float* n2w = (const float*)d_in[4];  // (C)
    const float* w21 = (const float*)d_in[5];  // (C,E)
    const float* b21 = (const float*)d_in[6];  // (E)
    const float* w22 = (const float*)d_in[7];  // (E,C)
    const float* b22 = (const float*)d_in[8];  // (C)
    float* out = (float*)d_out;                // (B,T,C) fp32

    char* ws = (char*)d_ws;
    const size_t MB = 1024ull * 1024ull;
    unsigned short* state = (unsigned short*)(ws);            // 32MB bf16; reused as hnorm
    unsigned short* w1T   = (unsigned short*)(ws + 32 * MB);  // 2MB  (C x C) bf16
    unsigned short* w21T  = (unsigned short*)(ws + 34 * MB);  // 8MB  (E x C) bf16
    unsigned short* w22T  = (unsigned short*)(ws + 42 * MB);  // 8MB  (C x E) bf16
    float* P              = (float*)(ws + 50 * MB);           // 1MB
    float* rinv           = (float*)(ws + 51 * MB);           // 64KB
    unsigned short* h     = (unsigned short*)(ws + 52 * MB);  // up to 128MB bf16 (sliced)
    float* out1 = out;  // gate*x lives in d_out (fp32); G3 reads then overwrites per-element

    // pick M-slice size for the h buffer based on available workspace
    int slice_rows = Mdim;  // 16384 -> h=128MB (total 180MB); halve until it fits
    while (52 * MB + (size_t)slice_rows * Edim * 2 > ws_size && slice_rows > 1024)
        slice_rows >>= 1;

    // weights -> bf16 (N x K)
    transpose_f2b<<<dim3(Cdim / 32, Cdim / 32), 256, 0, stream>>>(w1, w1T, Cdim, Cdim);
    transpose_f2b<<<dim3(Edim / 32, Cdim / 32), 256, 0, stream>>>(w21, w21T, Cdim, Edim);
    transpose_f2b<<<dim3(Cdim / 32, Edim / 32), 256, 0, stream>>>(w22, w22T, Edim, Cdim);

    // rmsnorm1 scale factors
    rms_inv_kernel<<<Mdim, 256, 0, stream>>>(x, rinv);

    // chunked cumsum of x*rinv*n1w over T, with triangular scaler -> bf16 state
    chunk_sums<<<1024, 256, 0, stream>>>(x, rinv, n1w, P);
    chunk_scan<<<32, 256, 0, stream>>>(P);
    cumsum_state<<<1024, 256, 0, stream>>>(x, rinv, n1w, P, state);

    // G1: out1 = sigmoid(state @ w1 + b1) * x   (fp32 out into d_out)
    gemm_bt<0><<<dim3(Cdim / 128, Mdim / 128), 256, 0, stream>>>(
        state, w1T, b1, x, out1, Mdim, Cdim, Cdim);

    // rmsnorm2(out1) -> bf16 hnorm (reuse state buffer)
    rmsnorm_f2b<<<Mdim, 256, 0, stream>>>(out1, n2w, state);

    // G2/G3 sliced over M to bound the h buffer
    for (int m0 = 0; m0 < Mdim; m0 += slice_rows) {
        gemm_bt<1><<<dim3(Edim / 128, slice_rows / 128), 256, 0, stream>>>(
            state + (size_t)m0 * Cdim, w21T, b21, nullptr, h, slice_rows, Edim, Cdim);
        gemm_bt<2><<<dim3(Cdim / 128, slice_rows / 128), 256, 0, stream>>>(
            h, w22T, b22, out1 + (size_t)m0 * Cdim, out + (size_t)m0 * Cdim,
            slice_rows, Cdim, Edim);
    }
}